// Round 1
// baseline (19011.798 us; speedup 1.0000x reference)
//
#include <hip/hip_runtime.h>

#define N_STEPS 2000
#define DT_F 0.01f

// tanh(x) = 1 - 2/(exp(2x)+1), via fast native exp + fast divide.
__device__ __forceinline__ float fast_tanh(float x) {
    float e = __expf(2.0f * x);
    return 1.0f - __fdividef(2.0f, e + 1.0f);
}

__global__ __launch_bounds__(256) void node_rk4_kernel(
    const float* __restrict__ y0_in,
    const float* __restrict__ W1, const float* __restrict__ B1,
    const float* __restrict__ W2, const float* __restrict__ B2,
    const float* __restrict__ W3, const float* __restrict__ B3,
    float* __restrict__ out, int batch)
{
    __shared__ float sW2[64 * 64];
    __shared__ __align__(16) float hbuf[4][64];

    const int tid  = threadIdx.x;
    const int lane = tid & 63;
    const int wib  = tid >> 6;                 // wave-in-block 0..3
    const int b    = blockIdx.x * 4 + wib;     // sample id

    // Stage W2 into LDS coalesced (once), then pull column `lane` to registers.
    for (int i = tid; i < 64 * 64; i += 256) sW2[i] = W2[i];
    __syncthreads();

    if (b >= batch) return;

    const int j = lane;
    const float w1_0 = W1[j], w1_1 = W1[64 + j];
    const float b1v  = B1[j], b2v  = B2[j];
    const float w3_0 = W3[2 * j], w3_1 = W3[2 * j + 1];
    const float b3_0 = B3[0], b3_1 = B3[1];

    float w2c[64];
    #pragma unroll
    for (int i = 0; i < 64; ++i) w2c[i] = sW2[i * 64 + j];  // W2[i][j]

    float y0 = y0_in[2 * b + 0];
    float y1 = y0_in[2 * b + 1];

    float* outb = out + (size_t)b * (2 * (N_STEPS + 1));
    if (lane == 0) {
        reinterpret_cast<float2*>(outb)[0] = make_float2(y0, y1);
    }

    float* hb = hbuf[wib];

    const float dt   = DT_F;
    const float hdt  = 0.5f * DT_F;
    const float dt6  = DT_F / 6.0f;

    // net: [wave-uniform y] -> [wave-uniform o]; lane j computes hidden unit j.
    auto net = [&](float yi0, float yi1, float& o0, float& o1) {
        float pre = fmaf(yi0, w1_0, fmaf(yi1, w1_1, b1v));
        float h1  = fast_tanh(pre);
        hb[lane] = h1;
        __builtin_amdgcn_wave_barrier();   // keep write->read ordering in-wave
        float a0 = b2v, a1 = 0.0f, a2 = 0.0f, a3 = 0.0f;
        #pragma unroll
        for (int i = 0; i < 64; i += 4) {
            float4 h4 = *reinterpret_cast<const float4*>(&hb[i]); // uniform addr: broadcast
            a0 = fmaf(h4.x, w2c[i + 0], a0);
            a1 = fmaf(h4.y, w2c[i + 1], a1);
            a2 = fmaf(h4.z, w2c[i + 2], a2);
            a3 = fmaf(h4.w, w2c[i + 3], a3);
        }
        __builtin_amdgcn_wave_barrier();   // reads done before next eval's write
        float h2 = fast_tanh((a0 + a1) + (a2 + a3));
        float p0 = h2 * w3_0;
        float p1 = h2 * w3_1;
        #pragma unroll
        for (int off = 32; off >= 1; off >>= 1) {
            p0 += __shfl_xor(p0, off, 64);
            p1 += __shfl_xor(p1, off, 64);
        }
        o0 = p0 + b3_0;
        o1 = p1 + b3_1;
    };

    for (int t = 1; t <= N_STEPS; ++t) {
        float k10, k11, k20, k21, k30, k31, k40, k41;
        net(y0, y1, k10, k11);
        net(fmaf(hdt, k10, y0), fmaf(hdt, k11, y1), k20, k21);
        net(fmaf(hdt, k20, y0), fmaf(hdt, k21, y1), k30, k31);
        net(fmaf(dt,  k30, y0), fmaf(dt,  k31, y1), k40, k41);
        float s0 = k10 + 2.0f * k20 + 2.0f * k30 + k40;
        float s1 = k11 + 2.0f * k21 + 2.0f * k31 + k41;
        y0 = fmaf(dt6, s0, y0);
        y1 = fmaf(dt6, s1, y1);
        if (lane == 0) {
            reinterpret_cast<float2*>(outb)[t] = make_float2(y0, y1);
        }
    }
}

extern "C" void kernel_launch(void* const* d_in, const int* in_sizes, int n_in,
                              void* d_out, int out_size, void* d_ws, size_t ws_size,
                              hipStream_t stream) {
    const float* y0 = (const float*)d_in[0];
    const float* W1 = (const float*)d_in[1];
    const float* B1 = (const float*)d_in[2];
    const float* W2 = (const float*)d_in[3];
    const float* B2 = (const float*)d_in[4];
    const float* W3 = (const float*)d_in[5];
    const float* B3 = (const float*)d_in[6];
    float* out = (float*)d_out;

    const int batch = in_sizes[0] / 2;
    const int blocks = (batch + 3) / 4;   // 4 waves (samples) per 256-thread block

    node_rk4_kernel<<<blocks, 256, 0, stream>>>(y0, W1, B1, W2, B2, W3, B3, out, batch);
}

// Round 2
// 18484.212 us; speedup vs baseline: 1.0285x; 1.0285x over previous
//
#include <hip/hip_runtime.h>

#define N_STEPS 2000
#define DT_F 0.01f

typedef float f32x2 __attribute__((ext_vector_type(2)));

// tanh(x) = 1 - 2/(exp(2x)+1), via fast native exp + fast divide.
__device__ __forceinline__ float fast_tanh(float x) {
    float e = __expf(2.0f * x);
    return 1.0f - __fdividef(2.0f, e + 1.0f);
}

__device__ __forceinline__ float rl(float v, int lane) {
    return __builtin_bit_cast(float, __builtin_amdgcn_readlane(__builtin_bit_cast(int, v), lane));
}

// DPP row_shr:n inclusive-scan step: v += shift-right-by-n within each row of 16
// (bound_ctrl=true -> lanes shifted past the row edge contribute 0).
#define DPP_SHR_ADD(v, n)                                                              \
    v += __builtin_bit_cast(float, __builtin_amdgcn_update_dpp(                        \
             0, __builtin_bit_cast(int, v), 0x110 | (n), 0xf, 0xf, true))

// Sum v across all 64 lanes; result returned as a wave-uniform float.
__device__ __forceinline__ float wave_sum(float v) {
    DPP_SHR_ADD(v, 1);
    DPP_SHR_ADD(v, 2);
    DPP_SHR_ADD(v, 4);
    DPP_SHR_ADD(v, 8);
    // lanes 15,31,47,63 now hold their row-of-16 sums
    return (rl(v, 15) + rl(v, 31)) + (rl(v, 47) + rl(v, 63));
}

__global__ __launch_bounds__(256, 4) void node_rk4_kernel(
    const float* __restrict__ y0_in,
    const float* __restrict__ W1, const float* __restrict__ B1,
    const float* __restrict__ W2, const float* __restrict__ B2,
    const float* __restrict__ W3, const float* __restrict__ B3,
    float* __restrict__ out, int batch)
{
    const int tid  = threadIdx.x;
    const int lane = tid & 63;
    const int wib  = tid >> 6;                 // wave-in-block 0..3
    const int b    = blockIdx.x * 4 + wib;     // sample id
    if (b >= batch) return;

    const int j = lane;
    const float w1_0 = W1[j], w1_1 = W1[64 + j];
    const float b1v  = B1[j], b2v  = B2[j];
    const float w3_0 = W3[2 * j], w3_1 = W3[2 * j + 1];
    const float b3_0 = B3[0], b3_1 = B3[1];

    // W2 column j as 32 packed pairs over the K dimension:
    // w2p[i] = { W2[2i][j], W2[2i+1][j] }  (coalesced loads across lanes)
    f32x2 w2p[32];
    #pragma unroll
    for (int i = 0; i < 32; ++i) {
        w2p[i].x = W2[(2 * i) * 64 + j];
        w2p[i].y = W2[(2 * i + 1) * 64 + j];
    }

    float y0 = y0_in[2 * b + 0];
    float y1 = y0_in[2 * b + 1];

    float* outb = out + (size_t)b * (2 * (N_STEPS + 1));
    if (lane == 0) {
        reinterpret_cast<float2*>(outb)[0] = make_float2(y0, y1);
    }

    const float dt  = DT_F;
    const float hdt = 0.5f * DT_F;
    const float dt6 = DT_F / 6.0f;

    // net: wave-uniform (yi0,yi1) -> wave-uniform (o0,o1); lane j owns hidden unit j.
    auto net = [&](float yi0, float yi1, float& o0, float& o1) {
        float pre = fmaf(yi0, w1_0, fmaf(yi1, w1_1, b1v));
        float h1  = fast_tanh(pre);

        f32x2 acc[4];
        acc[0] = (f32x2){b2v, 0.0f};
        acc[1] = (f32x2){0.0f, 0.0f};
        acc[2] = (f32x2){0.0f, 0.0f};
        acc[3] = (f32x2){0.0f, 0.0f};
        #pragma unroll
        for (int i = 0; i < 32; ++i) {
            f32x2 hp;
            hp.x = rl(h1, 2 * i);
            hp.y = rl(h1, 2 * i + 1);
            acc[i & 3] = __builtin_elementwise_fma(hp, w2p[i], acc[i & 3]);
        }
        f32x2 s4 = (acc[0] + acc[1]) + (acc[2] + acc[3]);
        float h2 = fast_tanh(s4.x + s4.y);

        o0 = wave_sum(h2 * w3_0) + b3_0;
        o1 = wave_sum(h2 * w3_1) + b3_1;
    };

    for (int t = 1; t <= N_STEPS; ++t) {
        float k10, k11, k20, k21, k30, k31, k40, k41;
        net(y0, y1, k10, k11);
        net(fmaf(hdt, k10, y0), fmaf(hdt, k11, y1), k20, k21);
        net(fmaf(hdt, k20, y0), fmaf(hdt, k21, y1), k30, k31);
        net(fmaf(dt,  k30, y0), fmaf(dt,  k31, y1), k40, k41);
        float s0 = k10 + 2.0f * k20 + 2.0f * k30 + k40;
        float s1 = k11 + 2.0f * k21 + 2.0f * k31 + k41;
        y0 = fmaf(dt6, s0, y0);
        y1 = fmaf(dt6, s1, y1);
        if (lane == 0) {
            reinterpret_cast<float2*>(outb)[t] = make_float2(y0, y1);
        }
    }
}

extern "C" void kernel_launch(void* const* d_in, const int* in_sizes, int n_in,
                              void* d_out, int out_size, void* d_ws, size_t ws_size,
                              hipStream_t stream) {
    const float* y0 = (const float*)d_in[0];
    const float* W1 = (const float*)d_in[1];
    const float* B1 = (const float*)d_in[2];
    const float* W2 = (const float*)d_in[3];
    const float* B2 = (const float*)d_in[4];
    const float* W3 = (const float*)d_in[5];
    const float* B3 = (const float*)d_in[6];
    float* out = (float*)d_out;

    const int batch = in_sizes[0] / 2;
    const int blocks = (batch + 3) / 4;   // 4 waves (samples) per 256-thread block

    node_rk4_kernel<<<blocks, 256, 0, stream>>>(y0, W1, B1, W2, B2, W3, B3, out, batch);
}

// Round 4
// 18261.360 us; speedup vs baseline: 1.0411x; 1.0122x over previous
//
#include <hip/hip_runtime.h>
#include <stdint.h>

#define N_STEPS 2000
#define DT_F 0.01f

typedef float f32x2 __attribute__((ext_vector_type(2)));

// tanh(x) = 1 - 2/(exp(2x)+1), via fast native exp + fast divide.
__device__ __forceinline__ float fast_tanh(float x) {
    float e = __expf(2.0f * x);
    return 1.0f - __fdividef(2.0f, e + 1.0f);
}

__device__ __forceinline__ float rl(float v, int lane) {
    return __builtin_bit_cast(float, __builtin_amdgcn_readlane(__builtin_bit_cast(int, v), lane));
}

// Pack lanes (l0, l0+1) of v into an SGPR pair (SALU pack — off the VALU pipe).
__device__ __forceinline__ uint64_t hpair(float v, int l0) {
    uint32_t a = (uint32_t)__builtin_amdgcn_readlane(__builtin_bit_cast(int, v), l0);
    uint32_t b = (uint32_t)__builtin_amdgcn_readlane(__builtin_bit_cast(int, v), l0 + 1);
    return ((uint64_t)b << 32) | (uint64_t)a;
}

// acc.{x,y} += hp.{lo,hi} * wp.{x,y}  — one VOP3P instr, SGPR-pair src0.
#define PKFMA(acc, hp, wp) \
    asm("v_pk_fma_f32 %0, %1, %2, %0" : "+v"(acc) : "s"(hp), "v"(wp))

template <int CTRL>
__device__ __forceinline__ float dpp_add(float v) {
    return v + __builtin_bit_cast(float, __builtin_amdgcn_update_dpp(
                   0, __builtin_bit_cast(int, v), CTRL, 0xf, 0xf, true));
}

// Sum v across 64 lanes; result valid in lane 63, extracted via readlane.
__device__ __forceinline__ float wave_sum(float v) {
    v = dpp_add<0x111>(v);  // row_shr:1
    v = dpp_add<0x112>(v);  // row_shr:2
    v = dpp_add<0x114>(v);  // row_shr:4
    v = dpp_add<0x118>(v);  // row_shr:8  -> lanes 15/31/47/63 hold row sums
    v = dpp_add<0x142>(v);  // row_bcast15: lane31=R0+R1, lane63=R2+R3
    v = dpp_add<0x143>(v);  // row_bcast31: lane63 += (R0+R1) -> full sum
    return rl(v, 63);
}

__global__ __launch_bounds__(256, 4) void node_rk4_kernel(
    const float* __restrict__ y0_in,
    const float* __restrict__ W1, const float* __restrict__ B1,
    const float* __restrict__ W2, const float* __restrict__ B2,
    const float* __restrict__ W3, const float* __restrict__ B3,
    float* __restrict__ out, int batch)
{
    const int tid  = threadIdx.x;
    const int lane = tid & 63;
    const int wib  = tid >> 6;                 // wave-in-block 0..3
    const int b    = blockIdx.x * 4 + wib;     // sample id
    if (b >= batch) return;

    const int j = lane;
    const float w1_0 = W1[j], w1_1 = W1[64 + j];
    const float b1v  = B1[j], b2v  = B2[j];
    const float w3_0 = W3[2 * j], w3_1 = W3[2 * j + 1];
    const float b3_0 = B3[0], b3_1 = B3[1];

    // W2 column j as 32 packed pairs over K: w2p[i] = { W2[2i][j], W2[2i+1][j] }
    f32x2 w2p[32];
    #pragma unroll
    for (int i = 0; i < 32; ++i) {
        w2p[i].x = W2[(2 * i) * 64 + j];
        w2p[i].y = W2[(2 * i + 1) * 64 + j];
    }

    float y0 = y0_in[2 * b + 0];
    float y1 = y0_in[2 * b + 1];

    float* outb = out + (size_t)b * (2 * (N_STEPS + 1));
    if (lane == 0) {
        reinterpret_cast<float2*>(outb)[0] = make_float2(y0, y1);
    }

    const float dt  = DT_F;
    const float hdt = 0.5f * DT_F;
    const float dt6 = DT_F / 6.0f;

    // net: wave-uniform (yi0,yi1) -> wave-uniform (o0,o1); lane j owns hidden unit j.
    auto net = [&](float yi0, float yi1, float& o0, float& o1) {
        float pre = fmaf(yi0, w1_0, fmaf(yi1, w1_1, b1v));
        float h1  = fast_tanh(pre);

        f32x2 acc[4];
        acc[0] = (f32x2){b2v, 0.0f};
        acc[1] = (f32x2){0.0f, 0.0f};
        acc[2] = (f32x2){0.0f, 0.0f};
        acc[3] = (f32x2){0.0f, 0.0f};
        #pragma unroll
        for (int i = 0; i < 32; ++i) {
            uint64_t hp = hpair(h1, 2 * i);
            PKFMA(acc[i & 3], hp, w2p[i]);
        }
        f32x2 s4 = (acc[0] + acc[1]) + (acc[2] + acc[3]);
        float h2 = fast_tanh(s4.x + s4.y);

        o0 = wave_sum(h2 * w3_0) + b3_0;
        o1 = wave_sum(h2 * w3_1) + b3_1;
    };

    for (int t = 1; t <= N_STEPS; ++t) {
        float k10, k11, k20, k21, k30, k31, k40, k41;
        net(y0, y1, k10, k11);
        net(fmaf(hdt, k10, y0), fmaf(hdt, k11, y1), k20, k21);
        net(fmaf(hdt, k20, y0), fmaf(hdt, k21, y1), k30, k31);
        net(fmaf(dt,  k30, y0), fmaf(dt,  k31, y1), k40, k41);
        float s0 = k10 + 2.0f * k20 + 2.0f * k30 + k40;
        float s1 = k11 + 2.0f * k21 + 2.0f * k31 + k41;
        y0 = fmaf(dt6, s0, y0);
        y1 = fmaf(dt6, s1, y1);
        if (lane == 0) {
            reinterpret_cast<float2*>(outb)[t] = make_float2(y0, y1);
        }
    }
}

extern "C" void kernel_launch(void* const* d_in, const int* in_sizes, int n_in,
                              void* d_out, int out_size, void* d_ws, size_t ws_size,
                              hipStream_t stream) {
    const float* y0 = (const float*)d_in[0];
    const float* W1 = (const float*)d_in[1];
    const float* B1 = (const float*)d_in[2];
    const float* W2 = (const float*)d_in[3];
    const float* B2 = (const float*)d_in[4];
    const float* W3 = (const float*)d_in[5];
    const float* B3 = (const float*)d_in[6];
    float* out = (float*)d_out;

    const int batch = in_sizes[0] / 2;
    const int blocks = (batch + 3) / 4;   // 4 waves (samples) per 256-thread block

    node_rk4_kernel<<<blocks, 256, 0, stream>>>(y0, W1, B1, W2, B2, W3, B3, out, batch);
}

// Round 5
// 10619.418 us; speedup vs baseline: 1.7903x; 1.7196x over previous
//
#include <hip/hip_runtime.h>
#include <stdint.h>

#define N_STEPS 2000
#define DT_F 0.01f

typedef float f32x2 __attribute__((ext_vector_type(2)));

// tanh(x) = 1 - 2/(exp2(2x*log2e)+1): mul, exp2, add, rcp, fma = 5 VALU.
__device__ __forceinline__ float fast_tanh(float x) {
    float e = __builtin_amdgcn_exp2f(x * 2.8853900817779268f);  // e^{2x}
    float r = __builtin_amdgcn_rcpf(e + 1.0f);
    return fmaf(-2.0f, r, 1.0f);
}

__device__ __forceinline__ float rl(float v, int lane) {
    return __builtin_bit_cast(float, __builtin_amdgcn_readlane(__builtin_bit_cast(int, v), lane));
}

// acc.{x,y} += hp.{x,y} * wp.{x,y} — one VOP3P instr, all-VGPR operands.
#define PKFMA(acc, hp, wp) \
    asm("v_pk_fma_f32 %0, %1, %2, %0" : "+v"(acc) : "v"(hp), "v"(wp))

template <int CTRL>
__device__ __forceinline__ float dpp_add(float v) {
    return v + __builtin_bit_cast(float, __builtin_amdgcn_update_dpp(
                   0, __builtin_bit_cast(int, v), CTRL, 0xf, 0xf, true));
}

// Sum v across 64 lanes; result extracted from lane 63.
__device__ __forceinline__ float wave_sum(float v) {
    v = dpp_add<0x111>(v);  // row_shr:1
    v = dpp_add<0x112>(v);  // row_shr:2
    v = dpp_add<0x114>(v);  // row_shr:4
    v = dpp_add<0x118>(v);  // row_shr:8  -> lanes 15/31/47/63 hold row sums
    v = dpp_add<0x142>(v);  // row_bcast15
    v = dpp_add<0x143>(v);  // row_bcast31 -> lane 63 = full sum
    return rl(v, 63);
}

__global__ __launch_bounds__(256, 4) void node_rk4_kernel(
    const float* __restrict__ y0_in,
    const float* __restrict__ W1, const float* __restrict__ B1,
    const float* __restrict__ W2, const float* __restrict__ B2,
    const float* __restrict__ W3, const float* __restrict__ B3,
    float* __restrict__ out, int batch)
{
    __shared__ __align__(16) float hl_all[4][64];

    const int tid  = threadIdx.x;
    const int lane = tid & 63;
    const int wib  = tid >> 6;                 // wave-in-block 0..3
    const int b    = blockIdx.x * 4 + wib;     // sample id
    if (b >= batch) return;

    const int j = lane;
    const float w1_0 = W1[j], w1_1 = W1[64 + j];
    const float b1v  = B1[j], b2v  = B2[j];
    const float w3_0 = W3[2 * j], w3_1 = W3[2 * j + 1];
    // Fold b3 into lane 0's pre-reduction term (saves SGPR->VGPR adds per eval).
    const float b3l0 = (lane == 0) ? B3[0] : 0.0f;
    const float b3l1 = (lane == 0) ? B3[1] : 0.0f;

    // W2 column j as 32 packed pairs over K: w2p[i] = { W2[2i][j], W2[2i+1][j] }
    f32x2 w2p[32];
    #pragma unroll
    for (int i = 0; i < 32; ++i) {
        w2p[i].x = W2[(2 * i) * 64 + j];
        w2p[i].y = W2[(2 * i + 1) * 64 + j];
    }

    float y0 = y0_in[2 * b + 0];
    float y1 = y0_in[2 * b + 1];

    float* outb = out + (size_t)b * (2 * (N_STEPS + 1));
    if (lane == 0) {
        reinterpret_cast<float2*>(outb)[0] = make_float2(y0, y1);
    }

    // Keep the dt constants in VGPRs so k (SGPR) can be the single scalar operand.
    float chdt = 0.5f * DT_F, cdt = DT_F, cdt6 = DT_F / 6.0f;
    asm("" : "+v"(chdt), "+v"(cdt), "+v"(cdt6));

    float* hl = hl_all[wib];
    const f32x2* hp2 = (const f32x2*)hl;

    // net: wave-uniform (yi0,yi1) -> wave-uniform (o0,o1); lane j owns hidden unit j.
    auto net = [&](float yi0, float yi1, float& o0, float& o1) {
        float pre = fmaf(yi0, w1_0, fmaf(yi1, w1_1, b1v));
        float h1  = fast_tanh(pre);
        hl[lane] = h1;
        __builtin_amdgcn_wave_barrier();   // write -> read ordering (in-wave)

        f32x2 acc0 = (f32x2){b2v, 0.0f};
        f32x2 acc1 = (f32x2){0.0f, 0.0f};
        f32x2 acc2 = (f32x2){0.0f, 0.0f};
        f32x2 acc3 = (f32x2){0.0f, 0.0f};
        #pragma unroll
        for (int i = 0; i < 32; i += 4) {
            f32x2 h0 = hp2[i + 0];   // uniform address: LDS broadcast, off VALU pipe
            f32x2 h1p = hp2[i + 1];
            f32x2 h2p = hp2[i + 2];
            f32x2 h3p = hp2[i + 3];
            PKFMA(acc0, h0,  w2p[i + 0]);
            PKFMA(acc1, h1p, w2p[i + 1]);
            PKFMA(acc2, h2p, w2p[i + 2]);
            PKFMA(acc3, h3p, w2p[i + 3]);
        }
        __builtin_amdgcn_wave_barrier();   // reads done before next eval's write

        f32x2 s4 = (acc0 + acc1) + (acc2 + acc3);
        float h2 = fast_tanh(s4.x + s4.y);
        float p0 = fmaf(h2, w3_0, b3l0);
        float p1 = fmaf(h2, w3_1, b3l1);
        o0 = wave_sum(p0);
        o1 = wave_sum(p1);
    };

    for (int t = 1; t <= N_STEPS; ++t) {
        float k10, k11, k20, k21, k30, k31, k40, k41;
        net(y0, y1, k10, k11);
        net(fmaf(chdt, k10, y0), fmaf(chdt, k11, y1), k20, k21);
        net(fmaf(chdt, k20, y0), fmaf(chdt, k21, y1), k30, k31);
        net(fmaf(cdt,  k30, y0), fmaf(cdt,  k31, y1), k40, k41);
        float s0 = (k10 + k40) + 2.0f * (k20 + k30);
        float s1 = (k11 + k41) + 2.0f * (k21 + k31);
        y0 = fmaf(cdt6, s0, y0);
        y1 = fmaf(cdt6, s1, y1);
        if (lane == 0) {
            reinterpret_cast<float2*>(outb)[t] = make_float2(y0, y1);
        }
    }
}

extern "C" void kernel_launch(void* const* d_in, const int* in_sizes, int n_in,
                              void* d_out, int out_size, void* d_ws, size_t ws_size,
                              hipStream_t stream) {
    const float* y0 = (const float*)d_in[0];
    const float* W1 = (const float*)d_in[1];
    const float* B1 = (const float*)d_in[2];
    const float* W2 = (const float*)d_in[3];
    const float* B2 = (const float*)d_in[4];
    const float* W3 = (const float*)d_in[5];
    const float* B3 = (const float*)d_in[6];
    float* out = (float*)d_out;

    const int batch = in_sizes[0] / 2;
    const int blocks = (batch + 3) / 4;   // 4 waves (samples) per 256-thread block

    node_rk4_kernel<<<blocks, 256, 0, stream>>>(y0, W1, B1, W2, B2, W3, B3, out, batch);
}